// Round 3
// baseline (666.988 us; speedup 1.0000x reference)
//
#include <hip/hip_runtime.h>

#define DEV __device__ __forceinline__

typedef _Float16 f16;
typedef _Float16 f16x8 __attribute__((ext_vector_type(8)));
typedef float f32x4 __attribute__((ext_vector_type(4)));

// ---------------------------------------------------------------- helpers

DEV void gload_lds16(const f16* g, f16* l) {
  // 16B-per-lane async global->LDS. LDS dest is wave-uniform base + lane*16.
  __builtin_amdgcn_global_load_lds(
      (const __attribute__((address_space(1))) void*)g,
      (__attribute__((address_space(3))) void*)l, 16, 0, 0);
}

// ---------------------------------------------------------------- prep

__global__ __launch_bounds__(256) void cast_f32_f16(const float* __restrict__ in,
                                                    f16* __restrict__ out, int n) {
  int i = (blockIdx.x * 256 + threadIdx.x) * 4;
  if (i < n) {
    float4 f = *(const float4*)(in + i);
    f16 o0 = (f16)f.x, o1 = (f16)f.y, o2 = (f16)f.z, o3 = (f16)f.w;
    f16* d = out + i;
    d[0] = o0; d[1] = o1; d[2] = o2; d[3] = o3;
  }
}

// transpose + cast 1024x1024 fp32 W -> f16 W^T   (z selects which weight)
__global__ __launch_bounds__(256) void transpose_cast(
    const float* s0, const float* s1, const float* s2, const float* s3,
    f16* d0, f16* d1, f16* d2, f16* d3) {
  const float* S[4] = {s0, s1, s2, s3};
  f16* D[4] = {d0, d1, d2, d3};
  const float* W = S[blockIdx.z];
  f16* WT = D[blockIdx.z];
  __shared__ float tile[32][33];
  int tx = threadIdx.x, ty = threadIdx.y;        // 32 x 8
  int r0 = blockIdx.y * 32, c0 = blockIdx.x * 32;
#pragma unroll
  for (int i = 0; i < 32; i += 8) tile[ty + i][tx] = W[(r0 + ty + i) * 1024 + c0 + tx];
  __syncthreads();
#pragma unroll
  for (int i = 0; i < 32; i += 8) WT[(c0 + ty + i) * 1024 + r0 + tx] = (f16)tile[tx][ty + i];
}

// ---------------------------------------------------------------- BT-GEMM core (m97)

DEV void gemm_bt_f16(const f16* __restrict__ A, const f16* __restrict__ B,
                     int lda, int ldb, int K, f16* As, f16* Bs, f32x4 (&acc)[4][4]) {
  const int t = threadIdx.x;
  const int l = t & 63, w = t >> 6;
  const int wm = w >> 1, wn = w & 1;
  const f16* ag = A + (t >> 2) * lda + (t & 3) * 8;
  const f16* bg = B + (t >> 2) * ldb + (t & 3) * 8;
  f16* asd = As + w * 512;
  f16* bsd = Bs + w * 512;
  const int arow = wm * 64 + (l & 15);
  const int brow = wn * 64 + (l & 15);
  const int ko = (l >> 4) * 8;
  for (int k0 = 0; k0 < K; k0 += 32) {
    __syncthreads();
    gload_lds16(ag + k0, asd);
    gload_lds16(ag + 64 * lda + k0, asd + 2048);
    gload_lds16(bg + k0, bsd);
    gload_lds16(bg + 64 * ldb + k0, bsd + 2048);
    __syncthreads();
    f16x8 af[4], bf[4];
#pragma unroll
    for (int i = 0; i < 4; i++) af[i] = *(const f16x8*)(As + (arow + i * 16) * 32 + ko);
#pragma unroll
    for (int j = 0; j < 4; j++) bf[j] = *(const f16x8*)(Bs + (brow + j * 16) * 32 + ko);
#pragma unroll
    for (int i = 0; i < 4; i++)
#pragma unroll
      for (int j = 0; j < 4; j++)
        acc[i][j] = __builtin_amdgcn_mfma_f32_16x16x32_f16(af[i], bf[j], acc[i][j], 0, 0, 0);
  }
}

// ---------------------------------------------------------------- K1: QKV projection

__global__ __launch_bounds__(256) void qkv_gemm(
    const f16* __restrict__ xb, const f16* __restrict__ WTq, const f16* __restrict__ WTk,
    const f16* __restrict__ WTv, const float* __restrict__ bq, const float* __restrict__ bk,
    const float* __restrict__ bv, f16* __restrict__ q, f16* __restrict__ kk,
    f16* __restrict__ vT) {
  __shared__ f16 As[128 * 32];
  __shared__ f16 Bs[128 * 32];
  __shared__ f16 tr[128 * 132];
  const int z = blockIdx.z;
  const f16* WT = (z == 0) ? WTq : ((z == 1) ? WTk : WTv);
  const float* bias = (z == 0) ? bq : ((z == 1) ? bk : bv);
  const int rowBase = blockIdx.y * 128, colBase = blockIdx.x * 128;
  f32x4 zero4 = {0.f, 0.f, 0.f, 0.f};
  f32x4 acc[4][4];
#pragma unroll
  for (int i = 0; i < 4; i++)
#pragma unroll
    for (int j = 0; j < 4; j++) acc[i][j] = zero4;
  gemm_bt_f16(xb + rowBase * 1024, WT + colBase * 1024, 1024, 1024, 1024, As, Bs, acc);
  const int t = threadIdx.x, l = t & 63, w = t >> 6, wm = w >> 1, wn = w & 1;
  if (z < 2) {
    f16* dst = (z == 0) ? q : kk;
#pragma unroll
    for (int i = 0; i < 4; i++)
#pragma unroll
      for (int j = 0; j < 4; j++)
#pragma unroll
        for (int r = 0; r < 4; r++) {
          int rt = wm * 64 + i * 16 + ((l >> 4) << 2) + r;
          int ct = wn * 64 + j * 16 + (l & 15);
          int rr = rowBase + rt, c = colBase + ct;
          float val = acc[i][j][r] + bias[c];
          int b = rr >> 10, n = rr & 1023, h = c >> 7, d = c & 127;
          dst[((b * 8 + h) * 1024 + n) * 128 + d] = (f16)val;
        }
  } else {
#pragma unroll
    for (int i = 0; i < 4; i++)
#pragma unroll
      for (int j = 0; j < 4; j++)
#pragma unroll
        for (int r = 0; r < 4; r++) {
          int rt = wm * 64 + i * 16 + ((l >> 4) << 2) + r;
          int ct = wn * 64 + j * 16 + (l & 15);
          tr[ct * 132 + rt] = (f16)(acc[i][j][r] + bias[colBase + ct]);
        }
    __syncthreads();
    int b = blockIdx.y >> 3, h = blockIdx.x;
    int nb = (blockIdx.y & 7) * 128;
    int head = b * 8 + h;
#pragma unroll
    for (int p = 0; p < 8; p++) {
      int lin = p * 2048 + t * 8;
      int c = lin >> 7, r = lin & 127;
      const f16* src = &tr[c * 132 + r];
      uint2 a0 = *(const uint2*)(src);
      uint2 a1 = *(const uint2*)(src + 4);
      f16* dst = vT + head * 131072 + c * 1024 + nb + r;
      *(uint2*)(dst) = a0;
      *(uint2*)(dst + 4) = a1;
    }
  }
}

// ---------------------------------------------------------------- K2: fused scores+entmax+PV
// One block = (head, 16-row q strip). 512 threads = 8 waves.
// Phase 1: S = q_strip @ K^T * SC  -> f16 strip Ps[16][1024] in LDS.
// Phase 2: entmax bisection per row (2 rows/wave, interleaved), write fp32 attn
//          to global, write p back to Ps as f16.
// Phase 3: ctx_strip = P @ V via BT-GEMM, A-frags straight from Ps.

#define PSLD 1032  // 1024 + 8 pad: keeps ds_read_b128 16B-aligned, conflict-free

__global__ __launch_bounds__(512, 4) void fused_attn(
    const f16* __restrict__ q, const f16* __restrict__ kk,
    const f16* __restrict__ vT, float* __restrict__ attn, f16* __restrict__ ctx) {
  __shared__ f16 Ps[16 * PSLD];   // 33 KB score/p strip
  __shared__ f16 Ks[128 * 128];   // 32 KB staging (K col-blocks, then V tiles)
  const int t = threadIdx.x, l = t & 63, w = t >> 6;
  const int head = blockIdx.y, n0 = blockIdx.x * 16;
  const int l15 = l & 15, l16 = l >> 4;

  // q A-fragments in registers (K=128 -> 4 frags)
  const f16* qh = q + head * 131072 + n0 * 128;
  f16x8 qf[4];
#pragma unroll
  for (int it = 0; it < 4; it++)
    qf[it] = *(const f16x8*)(qh + l15 * 128 + it * 32 + l16 * 8);

  // ---- phase 1: scores ------------------------------------------------
  const float SC = 0.04419417382415922f;  // (alpha-1)/sqrt(D) = 0.5/sqrt(128)
  const f16* kh = kk + head * 131072;
  for (int cb = 0; cb < 8; cb++) {
    __syncthreads();
    // stage K rows [cb*128 .. +128) x [128 d], 8-el chunks XOR-swizzled:
    // LDS slot s of row n holds global chunk s ^ (n&15)
#pragma unroll
    for (int c2 = 0; c2 < 4; c2++) {
      int n = c2 * 32 + (t >> 4);
      int ch = (t & 15) ^ (n & 15);
      gload_lds16(kh + (cb * 128 + n) * 128 + ch * 8, Ks + c2 * 4096 + w * 512);
    }
    __syncthreads();
    const int nrow = w * 16 + l15;
    f32x4 acc = {0.f, 0.f, 0.f, 0.f};
#pragma unroll
    for (int it = 0; it < 4; it++) {
      int g = it * 4 + l16;
      f16x8 bf = *(const f16x8*)(Ks + nrow * 128 + ((g ^ (nrow & 15)) * 8));
      acc = __builtin_amdgcn_mfma_f32_16x16x32_f16(qf[it], bf, acc, 0, 0, 0);
    }
    const int n = cb * 128 + nrow;
#pragma unroll
    for (int r = 0; r < 4; r++) {
      int m = l16 * 4 + r;
      Ps[m * PSLD + n] = (f16)(acc[r] * SC);
    }
  }

  // ---- phase 2: entmax bisection (2 rows per wave, interleaved) --------
  __syncthreads();
  {
    f16* r0p = Ps + (w * 2) * PSLD;
    f16* r1p = r0p + PSLD;
    float x0[16], x1[16];
#pragma unroll
    for (int j = 0; j < 16; j++) {
      x0[j] = (float)r0p[j * 64 + l];
      x1[j] = (float)r1p[j * 64 + l];
    }
    float m0 = x0[0], m1 = x1[0];
#pragma unroll
    for (int j = 1; j < 16; j++) { m0 = fmaxf(m0, x0[j]); m1 = fmaxf(m1, x1[j]); }
#pragma unroll
    for (int o = 32; o; o >>= 1) {
      m0 = fmaxf(m0, __shfl_xor(m0, o, 64));
      m1 = fmaxf(m1, __shfl_xor(m1, o, 64));
    }
    float lo0 = m0 - 1.0f, lo1 = m1 - 1.0f;
    float s0 = 0.f, s1 = 0.f;
#pragma unroll
    for (int j = 0; j < 16; j++) {
      float a = fmaxf(x0[j] - lo0, 0.f); s0 = fmaf(a, a, s0);
      float b = fmaxf(x1[j] - lo1, 0.f); s1 = fmaf(b, b, s1);
    }
#pragma unroll
    for (int o = 32; o; o >>= 1) { s0 += __shfl_xor(s0, o, 64); s1 += __shfl_xor(s1, o, 64); }
    const float fl0 = s0 - 1.0f, fl1 = s1 - 1.0f;
    float dm = 0.96875f;  // tau_hi - tau_lo = 1 - (1/1024)^(alpha-1)
    float tm0 = lo0, tm1 = lo1;
    for (int it = 0; it < 16; ++it) {
      dm *= 0.5f;
      tm0 = lo0 + dm; tm1 = lo1 + dm;
      float a0 = 0.f, a1 = 0.f;
#pragma unroll
      for (int j = 0; j < 16; j++) {
        float a = fmaxf(x0[j] - tm0, 0.f); a0 = fmaf(a, a, a0);
        float b = fmaxf(x1[j] - tm1, 0.f); a1 = fmaf(b, b, a1);
      }
#pragma unroll
      for (int o = 32; o; o >>= 1) { a0 += __shfl_xor(a0, o, 64); a1 += __shfl_xor(a1, o, 64); }
      if ((a0 - 1.0f) * fl0 >= 0.f) lo0 = tm0;
      if ((a1 - 1.0f) * fl1 >= 0.f) lo1 = tm1;
    }
    float q0 = 0.f, q1 = 0.f;
#pragma unroll
    for (int j = 0; j < 16; j++) {
      float a = fmaxf(x0[j] - tm0, 0.f); x0[j] = a * a; q0 += x0[j];
      float b = fmaxf(x1[j] - tm1, 0.f); x1[j] = b * b; q1 += x1[j];
    }
#pragma unroll
    for (int o = 32; o; o >>= 1) { q0 += __shfl_xor(q0, o, 64); q1 += __shfl_xor(q1, o, 64); }
    float i0 = 1.0f / q0, i1 = 1.0f / q1;
    float* a0p = attn + ((size_t)head * 1024 + n0 + w * 2) * 1024;
    float* a1p = a0p + 1024;
#pragma unroll
    for (int j = 0; j < 16; j++) {
      float v0 = x0[j] * i0, v1 = x1[j] * i1;
      a0p[j * 64 + l] = v0;
      a1p[j * 64 + l] = v1;
      r0p[j * 64 + l] = (f16)v0;
      r1p[j * 64 + l] = (f16)v1;
    }
  }

  // ---- phase 3: ctx = P @ V -------------------------------------------
  const f16* vh = vT + head * 131072;  // [128 d][1024 n]
  f16* Vs = Ks;
  f32x4 cacc = {0.f, 0.f, 0.f, 0.f};
  for (int k0 = 0; k0 < 1024; k0 += 64) {
    __syncthreads();
    // stage V tile [128 d][64 n], 8-el chunks XOR-swizzled: slot s of row d
    // holds global chunk s ^ (d&7)
#pragma unroll
    for (int c2 = 0; c2 < 2; c2++) {
      int d = c2 * 64 + (t >> 3);
      int ch = (t & 7) ^ (d & 7);
      gload_lds16(vh + d * 1024 + k0 + ch * 8, Vs + c2 * 4096 + w * 512);
    }
    __syncthreads();
    const int drow = w * 16 + l15;
#pragma unroll
    for (int kb = 0; kb < 2; kb++) {
      f16x8 af = *(const f16x8*)(Ps + l15 * PSLD + k0 + kb * 32 + l16 * 8);
      int g = kb * 4 + l16;
      f16x8 bf = *(const f16x8*)(Vs + drow * 64 + ((g ^ (drow & 7)) * 8));
      cacc = __builtin_amdgcn_mfma_f32_16x16x32_f16(af, bf, cacc, 0, 0, 0);
    }
  }
  const int b = head >> 3, h = head & 7;
#pragma unroll
  for (int r = 0; r < 4; r++) {
    int m = l16 * 4 + r;
    int d = w * 16 + l15;
    ctx[(size_t)(b * 1024 + n0 + m) * 1024 + h * 128 + d] = (f16)cacc[r];
  }
}

// ---------------------------------------------------------------- K3: out = ctx @ Wo + bo

__global__ __launch_bounds__(256) void out_gemm(const f16* __restrict__ ctx,
                                                const f16* __restrict__ WTo,
                                                const float* __restrict__ bo,
                                                float* __restrict__ out) {
  __shared__ f16 As[128 * 32];
  __shared__ f16 Bs[128 * 32];
  const int rowBase = blockIdx.y * 128, colBase = blockIdx.x * 128;
  f32x4 zero4 = {0.f, 0.f, 0.f, 0.f};
  f32x4 acc[4][4];
#pragma unroll
  for (int i = 0; i < 4; i++)
#pragma unroll
    for (int j = 0; j < 4; j++) acc[i][j] = zero4;
  gemm_bt_f16(ctx + rowBase * 1024, WTo + colBase * 1024, 1024, 1024, 1024, As, Bs, acc);
  const int l = threadIdx.x & 63, w = threadIdx.x >> 6, wm = w >> 1, wn = w & 1;
#pragma unroll
  for (int i = 0; i < 4; i++)
#pragma unroll
    for (int j = 0; j < 4; j++)
#pragma unroll
      for (int r = 0; r < 4; r++) {
        int rt = wm * 64 + i * 16 + ((l >> 4) << 2) + r;
        int ct = wn * 64 + j * 16 + (l & 15);
        out[(size_t)(rowBase + rt) * 1024 + colBase + ct] = acc[i][j][r] + bo[colBase + ct];
      }
}

// ---------------------------------------------------------------- launch

extern "C" void kernel_launch(void* const* d_in, const int* in_sizes, int n_in,
                              void* d_out, int out_size, void* d_ws, size_t ws_size,
                              hipStream_t stream) {
  const float* x  = (const float*)d_in[0];
  const float* Wq = (const float*)d_in[1];
  const float* bq = (const float*)d_in[2];
  const float* Wk = (const float*)d_in[3];
  const float* bk = (const float*)d_in[4];
  const float* Wv = (const float*)d_in[5];
  const float* bv = (const float*)d_in[6];
  const float* Wo = (const float*)d_in[7];
  const float* bo = (const float*)d_in[8];
  float* out = (float*)d_out;
  float* attn = out + 8388608;  // [64 heads][1024][1024] fp32 output

  char* ws = (char*)d_ws;
  f16* xb  = (f16*)(ws);                     // 16MB  (reused as ctx after qkv)
  f16* ctx = (f16*)(ws);                     // alias of xb
  f16* WTq = (f16*)(ws + (16u << 20));       // 2MB each
  f16* WTk = (f16*)(ws + (18u << 20));
  f16* WTv = (f16*)(ws + (20u << 20));
  f16* WTo = (f16*)(ws + (22u << 20));
  f16* q   = (f16*)(ws + (24u << 20));       // 16MB [64][1024][128]
  f16* kk  = (f16*)(ws + (40u << 20));       // 16MB
  f16* vT  = (f16*)(ws + (56u << 20));       // 16MB [64][128][1024]
  // total ws use: 72MB

  cast_f32_f16<<<dim3(8192), dim3(256), 0, stream>>>(x, xb, 8388608);
  transpose_cast<<<dim3(32, 32, 4), dim3(32, 8), 0, stream>>>(
      Wq, Wk, Wv, Wo, WTq, WTk, WTv, WTo);
  qkv_gemm<<<dim3(8, 64, 3), dim3(256), 0, stream>>>(
      xb, WTq, WTk, WTv, bq, bk, bv, q, kk, vT);
  fused_attn<<<dim3(64, 64), dim3(512), 0, stream>>>(q, kk, vT, attn, ctx);
  out_gemm<<<dim3(8, 64), dim3(256), 0, stream>>>(ctx, WTo, bo, out);
}

// Round 4
// 596.889 us; speedup vs baseline: 1.1174x; 1.1174x over previous
//
#include <hip/hip_runtime.h>

#define DEV __device__ __forceinline__

typedef _Float16 f16;
typedef _Float16 f16x8 __attribute__((ext_vector_type(8)));
typedef float f32x4 __attribute__((ext_vector_type(4)));

// ---------------------------------------------------------------- helpers

DEV void gload_lds16(const f16* g, f16* l) {
  // 16B-per-lane async global->LDS. LDS dest is wave-uniform base + lane*16.
  __builtin_amdgcn_global_load_lds(
      (const __attribute__((address_space(1))) void*)g,
      (__attribute__((address_space(3))) void*)l, 16, 0, 0);
}

// ---------------------------------------------------------------- prep

__global__ __launch_bounds__(256) void cast_f32_f16(const float* __restrict__ in,
                                                    f16* __restrict__ out, int n) {
  int i = (blockIdx.x * 256 + threadIdx.x) * 4;
  if (i < n) {
    float4 f = *(const float4*)(in + i);
    f16 o0 = (f16)f.x, o1 = (f16)f.y, o2 = (f16)f.z, o3 = (f16)f.w;
    f16* d = out + i;
    d[0] = o0; d[1] = o1; d[2] = o2; d[3] = o3;
  }
}

// transpose + cast 1024x1024 fp32 W -> f16 W^T   (z selects which weight)
__global__ __launch_bounds__(256) void transpose_cast(
    const float* s0, const float* s1, const float* s2, const float* s3,
    f16* d0, f16* d1, f16* d2, f16* d3) {
  const float* S[4] = {s0, s1, s2, s3};
  f16* D[4] = {d0, d1, d2, d3};
  const float* W = S[blockIdx.z];
  f16* WT = D[blockIdx.z];
  __shared__ float tile[32][33];
  int tx = threadIdx.x, ty = threadIdx.y;        // 32 x 8
  int r0 = blockIdx.y * 32, c0 = blockIdx.x * 32;
#pragma unroll
  for (int i = 0; i < 32; i += 8) tile[ty + i][tx] = W[(r0 + ty + i) * 1024 + c0 + tx];
  __syncthreads();
#pragma unroll
  for (int i = 0; i < 32; i += 8) WT[(c0 + ty + i) * 1024 + r0 + tx] = (f16)tile[tx][ty + i];
}

// ---------------------------------------------------------------- BT-GEMM core (m97)

DEV void gemm_bt_f16(const f16* __restrict__ A, const f16* __restrict__ B,
                     int lda, int ldb, int K, f16* As, f16* Bs, f32x4 (&acc)[4][4]) {
  const int t = threadIdx.x;
  const int l = t & 63, w = t >> 6;
  const int wm = w >> 1, wn = w & 1;
  const f16* ag = A + (t >> 2) * lda + (t & 3) * 8;
  const f16* bg = B + (t >> 2) * ldb + (t & 3) * 8;
  f16* asd = As + w * 512;
  f16* bsd = Bs + w * 512;
  const int arow = wm * 64 + (l & 15);
  const int brow = wn * 64 + (l & 15);
  const int ko = (l >> 4) * 8;
  for (int k0 = 0; k0 < K; k0 += 32) {
    __syncthreads();
    gload_lds16(ag + k0, asd);
    gload_lds16(ag + 64 * lda + k0, asd + 2048);
    gload_lds16(bg + k0, bsd);
    gload_lds16(bg + 64 * ldb + k0, bsd + 2048);
    __syncthreads();
    f16x8 af[4], bf[4];
#pragma unroll
    for (int i = 0; i < 4; i++) af[i] = *(const f16x8*)(As + (arow + i * 16) * 32 + ko);
#pragma unroll
    for (int j = 0; j < 4; j++) bf[j] = *(const f16x8*)(Bs + (brow + j * 16) * 32 + ko);
#pragma unroll
    for (int i = 0; i < 4; i++)
#pragma unroll
      for (int j = 0; j < 4; j++)
        acc[i][j] = __builtin_amdgcn_mfma_f32_16x16x32_f16(af[i], bf[j], acc[i][j], 0, 0, 0);
  }
}

// ---------------------------------------------------------------- K1: QKV projection

__global__ __launch_bounds__(256) void qkv_gemm(
    const f16* __restrict__ xb, const f16* __restrict__ WTq, const f16* __restrict__ WTk,
    const f16* __restrict__ WTv, const float* __restrict__ bq, const float* __restrict__ bk,
    const float* __restrict__ bv, f16* __restrict__ q, f16* __restrict__ kk,
    f16* __restrict__ vT) {
  __shared__ f16 As[128 * 32];
  __shared__ f16 Bs[128 * 32];
  __shared__ f16 tr[128 * 132];
  const int z = blockIdx.z;
  const f16* WT = (z == 0) ? WTq : ((z == 1) ? WTk : WTv);
  const float* bias = (z == 0) ? bq : ((z == 1) ? bk : bv);
  const int rowBase = blockIdx.y * 128, colBase = blockIdx.x * 128;
  f32x4 zero4 = {0.f, 0.f, 0.f, 0.f};
  f32x4 acc[4][4];
#pragma unroll
  for (int i = 0; i < 4; i++)
#pragma unroll
    for (int j = 0; j < 4; j++) acc[i][j] = zero4;
  gemm_bt_f16(xb + rowBase * 1024, WT + colBase * 1024, 1024, 1024, 1024, As, Bs, acc);
  const int t = threadIdx.x, l = t & 63, w = t >> 6, wm = w >> 1, wn = w & 1;
  if (z < 2) {
    f16* dst = (z == 0) ? q : kk;
#pragma unroll
    for (int i = 0; i < 4; i++)
#pragma unroll
      for (int j = 0; j < 4; j++)
#pragma unroll
        for (int r = 0; r < 4; r++) {
          int rt = wm * 64 + i * 16 + ((l >> 4) << 2) + r;
          int ct = wn * 64 + j * 16 + (l & 15);
          int rr = rowBase + rt, c = colBase + ct;
          float val = acc[i][j][r] + bias[c];
          int b = rr >> 10, n = rr & 1023, h = c >> 7, d = c & 127;
          dst[((b * 8 + h) * 1024 + n) * 128 + d] = (f16)val;
        }
  } else {
#pragma unroll
    for (int i = 0; i < 4; i++)
#pragma unroll
      for (int j = 0; j < 4; j++)
#pragma unroll
        for (int r = 0; r < 4; r++) {
          int rt = wm * 64 + i * 16 + ((l >> 4) << 2) + r;
          int ct = wn * 64 + j * 16 + (l & 15);
          tr[ct * 132 + rt] = (f16)(acc[i][j][r] + bias[colBase + ct]);
        }
    __syncthreads();
    int b = blockIdx.y >> 3, h = blockIdx.x;
    int nb = (blockIdx.y & 7) * 128;
    int head = b * 8 + h;
#pragma unroll
    for (int p = 0; p < 8; p++) {
      int lin = p * 2048 + t * 8;
      int c = lin >> 7, r = lin & 127;
      const f16* src = &tr[c * 132 + r];
      uint2 a0 = *(const uint2*)(src);
      uint2 a1 = *(const uint2*)(src + 4);
      f16* dst = vT + head * 131072 + c * 1024 + nb + r;
      *(uint2*)(dst) = a0;
      *(uint2*)(dst + 4) = a1;
    }
  }
}

// ---------------------------------------------------------------- K2: fused scores+entmax+PV, v2
// One block = (head, 32-row q strip). 512 threads = 8 waves. Barrier-free
// dataflow phases: B-fragments read DIRECTLY from global (no LDS staging, no
// per-tile barriers) so the compiler pipelines MFMA <-> VMEM with vmcnt.
// Only LDS: the 32x1024 f16 score/p strip (66 KB) -> 2 blocks/CU, 16 waves/CU.
// Phase 1: S = q_strip @ K^T * SC -> Ps.          (no barriers)
// Phase 2: entmax bisect, 4 rows/wave (2x ILP-2); write fp32 attn, p -> Ps.
// Phase 3: ctx_strip = P @ V, A-frags from Ps, V-frags from global. (no barriers)

#define PSLD 1032  // +8 pad: row stride 516 dw, l15 rows spread across bank groups

__global__ __launch_bounds__(512, 4) void fused_attn(
    const f16* __restrict__ q, const f16* __restrict__ kk,
    const f16* __restrict__ vT, float* __restrict__ attn, f16* __restrict__ ctx) {
  __shared__ f16 Ps[32 * PSLD];  // 66 KB
  const int t = threadIdx.x, l = t & 63, w = t >> 6;
  const int head = blockIdx.y, n0 = blockIdx.x * 32;
  const int l15 = l & 15, l16 = l >> 4;
  const int bb = head >> 3, hh = head & 7;
  const float SC = 0.04419417382415922f;  // (alpha-1)/sqrt(D) = 0.5/sqrt(128)

  const f16* qh = q + head * 131072;
  const f16* kh = kk + head * 131072;
  const f16* vh = vT + head * 131072;

  // q A-fragments for both m-tiles (rows n0..n0+31), kept in registers
  f16x8 qf[2][4];
#pragma unroll
  for (int mt = 0; mt < 2; mt++)
#pragma unroll
    for (int kb = 0; kb < 4; kb++)
      qf[mt][kb] = *(const f16x8*)(qh + (n0 + mt * 16 + l15) * 128 + kb * 32 + l16 * 8);

  // ---- phase 1: scores (wave w owns n-tiles w*8 .. w*8+7) ---------------
#pragma unroll 2
  for (int i = 0; i < 8; i++) {
    const int nt = w * 8 + i;
    f16x8 bf[4];
#pragma unroll
    for (int kb = 0; kb < 4; kb++)
      bf[kb] = *(const f16x8*)(kh + (nt * 16 + l15) * 128 + kb * 32 + l16 * 8);
    f32x4 acc[2] = {{0.f, 0.f, 0.f, 0.f}, {0.f, 0.f, 0.f, 0.f}};
#pragma unroll
    for (int mt = 0; mt < 2; mt++)
#pragma unroll
      for (int kb = 0; kb < 4; kb++)
        acc[mt] = __builtin_amdgcn_mfma_f32_16x16x32_f16(qf[mt][kb], bf[kb], acc[mt], 0, 0, 0);
#pragma unroll
    for (int mt = 0; mt < 2; mt++)
#pragma unroll
      for (int r = 0; r < 4; r++)
        Ps[(mt * 16 + l16 * 4 + r) * PSLD + nt * 16 + l15] = (f16)(acc[mt][r] * SC);
  }
  __syncthreads();

  // ---- phase 2: entmax (wave w owns rows w*4..w*4+3; two ILP-2 passes) --
  for (int p = 0; p < 2; p++) {
    f16* r0p = Ps + (size_t)(w * 4 + p * 2) * PSLD;
    f16* r1p = r0p + PSLD;
    f16x8 a0 = *(const f16x8*)(r0p + l * 8);
    f16x8 a1 = *(const f16x8*)(r0p + 512 + l * 8);
    f16x8 c0 = *(const f16x8*)(r1p + l * 8);
    f16x8 c1 = *(const f16x8*)(r1p + 512 + l * 8);
    float x0[16], x1[16];
#pragma unroll
    for (int e = 0; e < 8; e++) {
      x0[e] = (float)a0[e]; x0[8 + e] = (float)a1[e];
      x1[e] = (float)c0[e]; x1[8 + e] = (float)c1[e];
    }
    float m0 = x0[0], m1 = x1[0];
#pragma unroll
    for (int e = 1; e < 16; e++) { m0 = fmaxf(m0, x0[e]); m1 = fmaxf(m1, x1[e]); }
#pragma unroll
    for (int o = 32; o; o >>= 1) {
      m0 = fmaxf(m0, __shfl_xor(m0, o, 64));
      m1 = fmaxf(m1, __shfl_xor(m1, o, 64));
    }
    float lo0 = m0 - 1.0f, lo1 = m1 - 1.0f;
    float s0 = 0.f, s1 = 0.f;
#pragma unroll
    for (int e = 0; e < 16; e++) {
      float a = fmaxf(x0[e] - lo0, 0.f); s0 = fmaf(a, a, s0);
      float b = fmaxf(x1[e] - lo1, 0.f); s1 = fmaf(b, b, s1);
    }
#pragma unroll
    for (int o = 32; o; o >>= 1) { s0 += __shfl_xor(s0, o, 64); s1 += __shfl_xor(s1, o, 64); }
    const float fl0 = s0 - 1.0f, fl1 = s1 - 1.0f;
    float dm = 0.96875f;  // 1 - (1/1024)^(alpha-1)
    float tm0 = lo0, tm1 = lo1;
    for (int it = 0; it < 13; ++it) {
      dm *= 0.5f;
      tm0 = lo0 + dm; tm1 = lo1 + dm;
      float a0s = 0.f, a1s = 0.f;
#pragma unroll
      for (int e = 0; e < 16; e++) {
        float a = fmaxf(x0[e] - tm0, 0.f); a0s = fmaf(a, a, a0s);
        float b = fmaxf(x1[e] - tm1, 0.f); a1s = fmaf(b, b, a1s);
      }
#pragma unroll
      for (int o = 32; o; o >>= 1) { a0s += __shfl_xor(a0s, o, 64); a1s += __shfl_xor(a1s, o, 64); }
      if ((a0s - 1.0f) * fl0 >= 0.f) lo0 = tm0;
      if ((a1s - 1.0f) * fl1 >= 0.f) lo1 = tm1;
    }
    float q0 = 0.f, q1 = 0.f;
#pragma unroll
    for (int e = 0; e < 16; e++) {
      float a = fmaxf(x0[e] - tm0, 0.f); x0[e] = a * a; q0 += x0[e];
      float b = fmaxf(x1[e] - tm1, 0.f); x1[e] = b * b; q1 += x1[e];
    }
#pragma unroll
    for (int o = 32; o; o >>= 1) { q0 += __shfl_xor(q0, o, 64); q1 += __shfl_xor(q1, o, 64); }
    float i0 = 1.0f / q0, i1 = 1.0f / q1;
    float* a0p = attn + ((size_t)head * 1024 + n0 + w * 4 + p * 2) * 1024;
    float* a1p = a0p + 1024;
    float4 v0 = {x0[0] * i0, x0[1] * i0, x0[2] * i0, x0[3] * i0};
    float4 v1 = {x0[4] * i0, x0[5] * i0, x0[6] * i0, x0[7] * i0};
    float4 v2 = {x0[8] * i0, x0[9] * i0, x0[10] * i0, x0[11] * i0};
    float4 v3 = {x0[12] * i0, x0[13] * i0, x0[14] * i0, x0[15] * i0};
    float4 u0 = {x1[0] * i1, x1[1] * i1, x1[2] * i1, x1[3] * i1};
    float4 u1 = {x1[4] * i1, x1[5] * i1, x1[6] * i1, x1[7] * i1};
    float4 u2 = {x1[8] * i1, x1[9] * i1, x1[10] * i1, x1[11] * i1};
    float4 u3 = {x1[12] * i1, x1[13] * i1, x1[14] * i1, x1[15] * i1};
    *(float4*)(a0p + l * 8) = v0;
    *(float4*)(a0p + l * 8 + 4) = v1;
    *(float4*)(a0p + 512 + l * 8) = v2;
    *(float4*)(a0p + 512 + l * 8 + 4) = v3;
    *(float4*)(a1p + l * 8) = u0;
    *(float4*)(a1p + l * 8 + 4) = u1;
    *(float4*)(a1p + 512 + l * 8) = u2;
    *(float4*)(a1p + 512 + l * 8 + 4) = u3;
    f16x8 o0 = {(f16)v0.x, (f16)v0.y, (f16)v0.z, (f16)v0.w,
                (f16)v1.x, (f16)v1.y, (f16)v1.z, (f16)v1.w};
    f16x8 o1 = {(f16)v2.x, (f16)v2.y, (f16)v2.z, (f16)v2.w,
                (f16)v3.x, (f16)v3.y, (f16)v3.z, (f16)v3.w};
    f16x8 o2 = {(f16)u0.x, (f16)u0.y, (f16)u0.z, (f16)u0.w,
                (f16)u1.x, (f16)u1.y, (f16)u1.z, (f16)u1.w};
    f16x8 o3 = {(f16)u2.x, (f16)u2.y, (f16)u2.z, (f16)u2.w,
                (f16)u3.x, (f16)u3.y, (f16)u3.z, (f16)u3.w};
    *(f16x8*)(r0p + l * 8) = o0;
    *(f16x8*)(r0p + 512 + l * 8) = o1;
    *(f16x8*)(r1p + l * 8) = o2;
    *(f16x8*)(r1p + 512 + l * 8) = o3;
  }
  __syncthreads();

  // ---- phase 3: ctx = P @ V (wave w owns d-tile w; K=1024 dataflow) -----
  f32x4 cacc[2] = {{0.f, 0.f, 0.f, 0.f}, {0.f, 0.f, 0.f, 0.f}};
#pragma unroll 4
  for (int kb = 0; kb < 32; kb++) {
    f16x8 bfv = *(const f16x8*)(vh + (w * 16 + l15) * 1024 + kb * 32 + l16 * 8);
    f16x8 af0 = *(const f16x8*)(Ps + l15 * PSLD + kb * 32 + l16 * 8);
    f16x8 af1 = *(const f16x8*)(Ps + (16 + l15) * PSLD + kb * 32 + l16 * 8);
    cacc[0] = __builtin_amdgcn_mfma_f32_16x16x32_f16(af0, bfv, cacc[0], 0, 0, 0);
    cacc[1] = __builtin_amdgcn_mfma_f32_16x16x32_f16(af1, bfv, cacc[1], 0, 0, 0);
  }
#pragma unroll
  for (int mt = 0; mt < 2; mt++)
#pragma unroll
    for (int r = 0; r < 4; r++) {
      int m = mt * 16 + l16 * 4 + r;
      int d = w * 16 + l15;
      ctx[(size_t)(bb * 1024 + n0 + m) * 1024 + hh * 128 + d] = (f16)cacc[mt][r];
    }
}

// ---------------------------------------------------------------- K3: out = ctx @ Wo + bo

__global__ __launch_bounds__(256) void out_gemm(const f16* __restrict__ ctx,
                                                const f16* __restrict__ WTo,
                                                const float* __restrict__ bo,
                                                float* __restrict__ out) {
  __shared__ f16 As[128 * 32];
  __shared__ f16 Bs[128 * 32];
  const int rowBase = blockIdx.y * 128, colBase = blockIdx.x * 128;
  f32x4 zero4 = {0.f, 0.f, 0.f, 0.f};
  f32x4 acc[4][4];
#pragma unroll
  for (int i = 0; i < 4; i++)
#pragma unroll
    for (int j = 0; j < 4; j++) acc[i][j] = zero4;
  gemm_bt_f16(ctx + rowBase * 1024, WTo + colBase * 1024, 1024, 1024, 1024, As, Bs, acc);
  const int l = threadIdx.x & 63, w = threadIdx.x >> 6, wm = w >> 1, wn = w & 1;
#pragma unroll
  for (int i = 0; i < 4; i++)
#pragma unroll
    for (int j = 0; j < 4; j++)
#pragma unroll
      for (int r = 0; r < 4; r++) {
        int rt = wm * 64 + i * 16 + ((l >> 4) << 2) + r;
        int ct = wn * 64 + j * 16 + (l & 15);
        out[(size_t)(rowBase + rt) * 1024 + colBase + ct] = acc[i][j][r] + bo[colBase + ct];
      }
}

// ---------------------------------------------------------------- launch

extern "C" void kernel_launch(void* const* d_in, const int* in_sizes, int n_in,
                              void* d_out, int out_size, void* d_ws, size_t ws_size,
                              hipStream_t stream) {
  const float* x  = (const float*)d_in[0];
  const float* Wq = (const float*)d_in[1];
  const float* bq = (const float*)d_in[2];
  const float* Wk = (const float*)d_in[3];
  const float* bk = (const float*)d_in[4];
  const float* Wv = (const float*)d_in[5];
  const float* bv = (const float*)d_in[6];
  const float* Wo = (const float*)d_in[7];
  const float* bo = (const float*)d_in[8];
  float* out = (float*)d_out;
  float* attn = out + 8388608;  // [64 heads][1024][1024] fp32 output

  char* ws = (char*)d_ws;
  f16* xb  = (f16*)(ws);                     // 16MB  (reused as ctx after qkv)
  f16* ctx = (f16*)(ws);                     // alias of xb
  f16* WTq = (f16*)(ws + (16u << 20));       // 2MB each
  f16* WTk = (f16*)(ws + (18u << 20));
  f16* WTv = (f16*)(ws + (20u << 20));
  f16* WTo = (f16*)(ws + (22u << 20));
  f16* q   = (f16*)(ws + (24u << 20));       // 16MB [64][1024][128]
  f16* kk  = (f16*)(ws + (40u << 20));       // 16MB
  f16* vT  = (f16*)(ws + (56u << 20));       // 16MB [64][128][1024]
  // total ws use: 72MB

  cast_f32_f16<<<dim3(8192), dim3(256), 0, stream>>>(x, xb, 8388608);
  transpose_cast<<<dim3(32, 32, 4), dim3(32, 8), 0, stream>>>(
      Wq, Wk, Wv, Wo, WTq, WTk, WTv, WTo);
  qkv_gemm<<<dim3(8, 64, 3), dim3(256), 0, stream>>>(
      xb, WTq, WTk, WTv, bq, bk, bv, q, kk, vT);
  fused_attn<<<dim3(32, 64), dim3(512), 0, stream>>>(q, kk, vT, attn, ctx);
  out_gemm<<<dim3(8, 64), dim3(256), 0, stream>>>(ctx, WTo, bo, out);
}